// Round 1
// 313.827 us; speedup vs baseline: 1.0195x; 1.0195x over previous
//
#include <hip/hip_runtime.h>

// Problem constants (from reference)
#define B_ 2048
#define S_ 200
#define D_ 128
#define H_ 64
#define MASK_SCALE 1e10f

typedef __attribute__((ext_vector_type(8))) short short8_t;            // 8 bf16 in 4 VGPRs
typedef __attribute__((ext_vector_type(4))) float f32x4;
typedef __attribute__((ext_vector_type(4))) unsigned short ushort4_t;  // 8B

__device__ __forceinline__ unsigned short f2bf(float f) {
    unsigned u = __float_as_uint(f);
    unsigned r = (u + 0x7fffu + ((u >> 16) & 1u)) >> 16;   // round-to-nearest-even
    return (unsigned short)r;
}
__device__ __forceinline__ float bf2f(unsigned short v) {
    return __uint_as_float(((unsigned)v) << 16);
}
// packed f32x2 -> bf16x2, RNE, 1 instruction (replaces ~9 VALU ops of f2bf pair)
__device__ __forceinline__ unsigned cvt_pk_bf16(float lo, float hi) {
    unsigned r;
    asm("v_cvt_pk_bf16_f32 %0, %1, %2" : "=v"(r) : "v"(lo), "v"(hi));
    return r;
}

// ---------------------------------------------------------------------------
// prep: 32 blocks. Each thread owns one (d, h) of the 128x64 weight tile:
//   wfrag: Wh = (W1+W2) in bf16, MFMA B-fragment order (16 KB)
//   w23t : transposed (W3-W2), [h][d] fp32 (32 KB) -- consumed per-block in
//          fused to build tproj inline (replaces the old 512-block tproj pass
//          and its 512 KB HBM round-trip).
// ---------------------------------------------------------------------------
__global__ __launch_bounds__(256) void prep(const float* __restrict__ W,
                                            unsigned short* __restrict__ wfrag,
                                            float* __restrict__ w23t) {
    int idx = blockIdx.x * 256 + threadIdx.x;   // 0..8191
    int d = idx >> 6;                           // 0..127
    int h = idx & 63;                           // 0..63
    float w1 = W[d * H_ + h];
    float w2 = W[(D_ + d) * H_ + h];
    float w3 = W[(2 * D_ + d) * H_ + h];
    int kt = d >> 5, q = (d >> 3) & 3, j = d & 7;
    int nt = h >> 4, lm = h & 15;
    int lane = (q << 4) | lm;
    wfrag[((kt * 4 + nt) * 64 + lane) * 8 + j] = f2bf(w1 + w2);
    w23t[h * D_ + d] = w3 - w2;
}

// ---------------------------------------------------------------------------
// Fused: one block per batch, 3 blocks/CU (51.2 KB his tile, XOR-swizzled).
// Stage his[b] -> LDS bf16 (batched float4, cvt_pk), tproj inline (partials
// through LDS using the staging barrier), MFMA alpha, block softmax,
// weighted pool from LDS.
// LDS layout: row s = 256 B = 16 chunks of 16 B; chunk c stored at c^(s&15).
// tpp[4][64] aliases pool_s[0..255]: tpp reads finish right after the staging
// barrier (before the tile loop); pool writes happen after the softmax
// barriers -- lifetimes are barrier-separated.
// ---------------------------------------------------------------------------
__global__ __launch_bounds__(256, 3) void fused_kernel(const float* __restrict__ his,
                                                       const float* __restrict__ mask,
                                                       const float* __restrict__ target,
                                                       const float* __restrict__ W_bias,
                                                       const unsigned short* __restrict__ wfrag,
                                                       const float* __restrict__ w23t,
                                                       const float* __restrict__ Ovec,
                                                       float* __restrict__ out) {
    __shared__ unsigned short hisb[S_ * D_];        // 51,200 B, swizzled
    __shared__ float alpha_s[208];                  // 13 tiles x 16 rows
    __shared__ float red8[8];
    __shared__ float ov_s[H_];
    __shared__ float pool_s[3 * D_];                // 1536 B; [0..255] doubles as tpp[4][64]
    float* tpp = pool_s;

    const int b    = blockIdx.x;
    const int t    = threadIdx.x;
    const int lane = t & 63;
    const int wv   = t >> 6;
    const int lm   = lane & 15;
    const int q    = lane >> 4;

    // small loads in flight early
    float mk = (t < S_) ? mask[(size_t)b * S_ + t] : 0.f;
    if (t < H_) ov_s[t] = Ovec[t];

    // ---- tproj partial: h = lane, d-chunk = wv*32..wv*32+31 (w23t L2-resident) ----
    {
        float acc = (wv == 0) ? W_bias[lane] : 0.f;
        const float4* tg4 = (const float4*)(target + (size_t)b * D_) + wv * 8;
        const float4* wt4 = (const float4*)(w23t + lane * D_) + wv * 8;
        #pragma unroll
        for (int i = 0; i < 8; ++i) {
            float4 tv = tg4[i];
            float4 wc = wt4[i];
            acc = fmaf(tv.x, wc.x, acc);
            acc = fmaf(tv.y, wc.y, acc);
            acc = fmaf(tv.z, wc.z, acc);
            acc = fmaf(tv.w, wc.w, acc);
        }
        tpp[wv * 64 + lane] = acc;
    }

    // B fragments: 16 x 16B per lane (L2-resident, same for all blocks)
    short8_t bfrag[16];
    #pragma unroll
    for (int f = 0; f < 16; ++f)
        bfrag[f] = *(const short8_t*)(wfrag + ((size_t)(f * 64 + lane)) * 8);

    // ---- stage his[b] -> LDS bf16: 25 float4/thread, 5 batches of 5 ----
    const float4* hb4 = (const float4*)(his + (size_t)b * S_ * D_);
    #pragma unroll
    for (int g = 0; g < 5; ++g) {
        float4 x[5];
        #pragma unroll
        for (int j = 0; j < 5; ++j)
            x[j] = hb4[t + (g * 5 + j) * 256];
        #pragma unroll
        for (int j = 0; j < 5; ++j) {
            int i  = t + (g * 5 + j) * 256;
            int s  = i >> 5;                 // row
            int d8 = i & 31;                 // 8B index in row
            int pc = (d8 >> 1) ^ (s & 15);   // swizzled 16B chunk
            uint2 v;
            v.x = cvt_pk_bf16(x[j].x, x[j].y);
            v.y = cvt_pk_bf16(x[j].z, x[j].w);
            *(uint2*)((char*)hisb + s * 256 + pc * 16 + (d8 & 1) * 8) = v;
        }
    }
    __syncthreads();

    // reduce tproj partials into registers (tpp dead after this point)
    float th[4];
    #pragma unroll
    for (int nt = 0; nt < 4; ++nt) {
        int h = nt * 16 + lm;
        th[nt] = tpp[h] + tpp[64 + h] + tpp[128 + h] + tpp[192 + h];
    }

    // ---- alpha via MFMA: 13 tiles of 16 rows over 4 waves ----
    for (int tile = wv; tile < 13; tile += 4) {
        int row0 = tile * 16;
        int ar = row0 + lm; if (ar > S_ - 1) ar = S_ - 1;   // clamp pad rows

        f32x4 acc[4];
        #pragma unroll
        for (int nt = 0; nt < 4; ++nt) acc[nt] = (f32x4){0.f, 0.f, 0.f, 0.f};

        #pragma unroll
        for (int kt = 0; kt < 4; ++kt) {
            int c = (kt * 4 + q) ^ (ar & 15);
            short8_t a = *(const short8_t*)((const char*)hisb + ar * 256 + c * 16);
            #pragma unroll
            for (int nt = 0; nt < 4; ++nt)
                acc[nt] = __builtin_amdgcn_mfma_f32_16x16x32_bf16(a, bfrag[kt * 4 + nt], acc[nt], 0, 0, 0);
        }

        // epilogue: +tproj, relu, dot O (O_bias softmax-invariant -> skipped)
        float part[4];
        #pragma unroll
        for (int r = 0; r < 4; ++r) {
            float sum = 0.f;
            #pragma unroll
            for (int nt = 0; nt < 4; ++nt) {
                int h = nt * 16 + lm;
                float v = acc[nt][r] + th[nt];
                v = fmaxf(v, 0.f);
                sum = fmaf(v, ov_s[h], sum);
            }
            part[r] = sum;
        }
        #pragma unroll
        for (int off = 1; off < 16; off <<= 1) {
            #pragma unroll
            for (int r = 0; r < 4; ++r)
                part[r] += __shfl_xor(part[r], off);
        }
        if (lm == 0) {
            #pragma unroll
            for (int r = 0; r < 4; ++r)
                alpha_s[row0 + q * 4 + r] = part[r];
        }
    }
    __syncthreads();

    // ---- block softmax over s = 0..199 ----
    float a = (t < S_) ? alpha_s[t] - mk * MASK_SCALE : -INFINITY;
    float m = a;
    #pragma unroll
    for (int off = 1; off < 64; off <<= 1) m = fmaxf(m, __shfl_xor(m, off));
    if (lane == 0) red8[wv] = m;
    __syncthreads();
    m = fmaxf(fmaxf(red8[0], red8[1]), fmaxf(red8[2], red8[3]));
    float e = (t < S_) ? __expf(a - m) : 0.f;
    float ssum = e;
    #pragma unroll
    for (int off = 1; off < 64; off <<= 1) ssum += __shfl_xor(ssum, off);
    if (lane == 0) red8[4 + wv] = ssum;
    __syncthreads();
    float inv = 1.f / (red8[4] + red8[5] + red8[6] + red8[7]);
    __syncthreads();                 // alpha_s reads done before overwrite below
    if (t < S_) alpha_s[t] = e * inv;
    __syncthreads();

    // ---- pooling: out[b][d] = sum_s w[s] * his_bf[s][d] ----
    const int d8 = t & 31;           // 8B index: covers d = d8*4 .. d8*4+3
    const int sg = t >> 5;           // 0..7 s-groups
    float acc0 = 0.f, acc1 = 0.f, acc2 = 0.f, acc3 = 0.f;
    #pragma unroll 5
    for (int s = sg; s < S_; s += 8) {
        float w = alpha_s[s];        // half-wave-uniform broadcast
        int pc = (d8 >> 1) ^ (s & 15);
        ushort4_t v = *(const ushort4_t*)((const char*)hisb + s * 256 + pc * 16 + (d8 & 1) * 8);
        acc0 = fmaf(w, bf2f(v[0]), acc0);
        acc1 = fmaf(w, bf2f(v[1]), acc1);
        acc2 = fmaf(w, bf2f(v[2]), acc2);
        acc3 = fmaf(w, bf2f(v[3]), acc3);
    }
    // combine the two s-groups within each wave
    acc0 += __shfl_xor(acc0, 32);
    acc1 += __shfl_xor(acc1, 32);
    acc2 += __shfl_xor(acc2, 32);
    acc3 += __shfl_xor(acc3, 32);
    if (wv && lane < 32) {
        float4 p; p.x = acc0; p.y = acc1; p.z = acc2; p.w = acc3;
        *(float4*)(&pool_s[(wv - 1) * D_ + d8 * 4]) = p;
    }
    __syncthreads();
    if (wv == 0 && lane < 32) {
        #pragma unroll
        for (int k = 0; k < 3; ++k) {
            const float4 p = *(const float4*)(&pool_s[k * D_ + d8 * 4]);
            acc0 += p.x; acc1 += p.y; acc2 += p.z; acc3 += p.w;
        }
        float4 o; o.x = acc0; o.y = acc1; o.z = acc2; o.w = acc3;
        *(float4*)(out + (size_t)b * D_ + d8 * 4) = o;
    }
}

// ---------------------------------------------------------------------------
extern "C" void kernel_launch(void* const* d_in, const int* in_sizes, int n_in,
                              void* d_out, int out_size, void* d_ws, size_t ws_size,
                              hipStream_t stream) {
    const float* his    = (const float*)d_in[0];
    const float* target = (const float*)d_in[1];
    const float* mask   = (const float*)d_in[2];
    const float* W      = (const float*)d_in[3];
    const float* W_bias = (const float*)d_in[4];
    const float* Ovec   = (const float*)d_in[5];
    // O_bias (d_in[6]) is softmax-invariant -> unused
    float* out = (float*)d_out;

    char* ws = (char*)d_ws;
    unsigned short* wfrag = (unsigned short*)ws;           // 16 KB
    float* w23t           = (float*)(ws + 16384);          // 32 KB, (W3-W2)^T [h][d]

    prep<<<32, 256, 0, stream>>>(W, wfrag, w23t);
    fused_kernel<<<B_, 256, 0, stream>>>(his, mask, target, W_bias, wfrag, w23t, Ovec, out);
}

// Round 2
// 302.485 us; speedup vs baseline: 1.0578x; 1.0375x over previous
//
#include <hip/hip_runtime.h>

// Problem constants (from reference)
#define B_ 2048
#define S_ 200
#define D_ 128
#define H_ 64
#define KB_ 8                  // batches per persistent block
#define GRID_ (B_ / KB_)       // 256 blocks = 1 per CU (LDS-forced)
#define MASK_SCALE 1e10f

typedef __attribute__((ext_vector_type(8))) short short8_t;            // 8 bf16 in 4 VGPRs
typedef __attribute__((ext_vector_type(4))) float f32x4;
typedef __attribute__((ext_vector_type(4))) unsigned short ushort4_t;  // 8B

__device__ __forceinline__ unsigned short f2bf(float f) {
    unsigned u = __float_as_uint(f);
    unsigned r = (u + 0x7fffu + ((u >> 16) & 1u)) >> 16;   // round-to-nearest-even
    return (unsigned short)r;
}
__device__ __forceinline__ float bf2f(unsigned short v) {
    return __uint_as_float(((unsigned)v) << 16);
}
// packed f32x2 -> bf16x2, RNE, 1 instruction
__device__ __forceinline__ unsigned cvt_pk_bf16(float lo, float hi) {
    unsigned r;
    asm("v_cvt_pk_bf16_f32 %0, %1, %2" : "=v"(r) : "v"(lo), "v"(hi));
    return r;
}
// Barrier that does NOT drain vmcnt: lets prefetch loads stay in flight.
// LDS ops are drained (lgkmcnt) for cross-wave visibility; single asm block
// so nothing can be scheduled between the wait and the barrier.
__device__ __forceinline__ void bar() {
    asm volatile("s_waitcnt lgkmcnt(0)\n\ts_barrier" ::: "memory");
}

// ---------------------------------------------------------------------------
// prep: 32 blocks. Each thread owns one (d, h) of the 128x64 weight tile:
//   wfrag: Wh = (W1+W2) in bf16, MFMA B-fragment order (16 KB)
//   w23t : transposed (W3-W2), [h][d] fp32 (32 KB)
// ---------------------------------------------------------------------------
__global__ __launch_bounds__(256) void prep(const float* __restrict__ W,
                                            unsigned short* __restrict__ wfrag,
                                            float* __restrict__ w23t) {
    int idx = blockIdx.x * 256 + threadIdx.x;   // 0..8191
    int d = idx >> 6;                           // 0..127
    int h = idx & 63;                           // 0..63
    float w1 = W[d * H_ + h];
    float w2 = W[(D_ + d) * H_ + h];
    float w3 = W[(2 * D_ + d) * H_ + h];
    int kt = d >> 5, q = (d >> 3) & 3, j = d & 7;
    int nt = h >> 4, lm = h & 15;
    int lane = (q << 4) | lm;
    wfrag[((kt * 4 + nt) * 64 + lane) * 8 + j] = f2bf(w1 + w2);
    w23t[h * D_ + d] = w3 - w2;
}

// ---------------------------------------------------------------------------
// Persistent fused kernel: 256 blocks x 512 threads, 8 batches each,
// double-buffered his tile (2 x 51.2 KB, XOR-swizzled bf16).
// Per iteration: prefetch next batch's his/target/mask to REGISTERS first,
// then MFMA alpha + softmax + pool current buffer (loads in flight across
// the raw barriers), then convert+ds_write next buffer + next tproj partials.
// Steady state is pure HBM-bound: max(10K cyc mem, ~2.5K cyc compute).
// ---------------------------------------------------------------------------
__global__ __launch_bounds__(512, 2) void fused_kernel(const float* __restrict__ his,
                                                       const float* __restrict__ mask,
                                                       const float* __restrict__ target,
                                                       const float* __restrict__ W_bias,
                                                       const unsigned short* __restrict__ wfrag,
                                                       const float* __restrict__ w23t,
                                                       const float* __restrict__ Ovec,
                                                       float* __restrict__ out) {
    __shared__ unsigned short hisb[2][S_ * D_];     // 2 x 51,200 B, swizzled
    __shared__ float alph[208];                     // raw alpha (13 tiles x 16)
    __shared__ float attw[208];                     // exp(a - m), unnormalized
    __shared__ float red8[8];                       // per-wave max
    __shared__ float red8b[8];                      // per-wave expsum
    __shared__ float ov_s[H_];
    __shared__ float tpp[8 * H_];                   // tproj partials [wave][h]
    __shared__ float pool_s[7 * D_];                // pooling cross-wave partials

    const int t    = threadIdx.x;
    const int lane = t & 63;
    const int wv   = t >> 6;       // 0..7
    const int lm   = lane & 15;
    const int q    = lane >> 4;
    const int b0   = blockIdx.x * KB_;

    if (t < H_) ov_s[t] = Ovec[t];
    const float wb = (wv == 0) ? W_bias[lane] : 0.f;

    // persistent weight registers
    short8_t bfrag[16];                       // MFMA B fragments (64 VGPR)
    #pragma unroll
    for (int f = 0; f < 16; ++f)
        bfrag[f] = *(const short8_t*)(wfrag + ((size_t)(f * 64 + lane)) * 8);
    float4 wsl[4];                            // (W3-W2)^T[h=lane][d=wv*16..+15]
    #pragma unroll
    for (int k = 0; k < 4; ++k)
        wsl[k] = *(const float4*)(w23t + lane * D_ + wv * 16 + k * 4);

    // ---- prologue: stage batch b0 into buffer 0 ----
    float mk;
    {
        const float4* hb4 = (const float4*)(his + (size_t)b0 * S_ * D_);
        float4 x0[13];
        #pragma unroll
        for (int j = 0; j < 13; ++j) {
            int i = t + j * 512;
            if (i < 6400) x0[j] = hb4[i];
        }
        mk = (t < S_) ? mask[(size_t)b0 * S_ + t] : 0.f;
        const float4* tg4 = (const float4*)(target + (size_t)b0 * D_) + wv * 4;
        float acc = wb;
        #pragma unroll
        for (int k = 0; k < 4; ++k) {
            float4 tv = tg4[k];
            acc = fmaf(tv.x, wsl[k].x, acc);
            acc = fmaf(tv.y, wsl[k].y, acc);
            acc = fmaf(tv.z, wsl[k].z, acc);
            acc = fmaf(tv.w, wsl[k].w, acc);
        }
        tpp[wv * 64 + lane] = acc;
        #pragma unroll
        for (int j = 0; j < 13; ++j) {
            int i = t + j * 512;
            if (i < 6400) {
                int s = i >> 5, d8 = i & 31;
                int pc = (d8 >> 1) ^ (s & 15);
                uint2 v;
                v.x = cvt_pk_bf16(x0[j].x, x0[j].y);
                v.y = cvt_pk_bf16(x0[j].z, x0[j].w);
                *(uint2*)((char*)hisb[0] + s * 256 + pc * 16 + (d8 & 1) * 8) = v;
            }
        }
    }
    __syncthreads();

    int cur = 0;
    for (int n = 0; n < KB_; ++n) {
        const int b = b0 + n;
        const bool more = (n + 1 < KB_);
        const unsigned short* hb = hisb[cur];

        // tproj for this batch from LDS partials
        float th[4];
        #pragma unroll
        for (int nt = 0; nt < 4; ++nt) {
            int h = nt * 16 + lm;
            float s0 = tpp[h] + tpp[64 + h] + tpp[128 + h] + tpp[192 + h];
            float s1 = tpp[256 + h] + tpp[320 + h] + tpp[384 + h] + tpp[448 + h];
            th[nt] = s0 + s1;
        }

        // ---- issue next-batch loads (stay in flight across barriers) ----
        float4 x[13];
        float4 tg[4];
        float mkn = 0.f;
        if (more) {
            const float4* hb4n = (const float4*)(his + (size_t)(b + 1) * S_ * D_);
            #pragma unroll
            for (int j = 0; j < 13; ++j) {
                int i = t + j * 512;
                if (i < 6400) x[j] = hb4n[i];
            }
            const float4* tg4 = (const float4*)(target + (size_t)(b + 1) * D_) + wv * 4;
            #pragma unroll
            for (int k = 0; k < 4; ++k) tg[k] = tg4[k];
            if (t < S_) mkn = mask[(size_t)(b + 1) * S_ + t];
        }

        // ---- alpha via MFMA: 13 tiles over 8 waves ----
        #pragma unroll
        for (int tt = 0; tt < 2; ++tt) {
            int tile = wv + tt * 8;
            if (tile < 13) {
                int row0 = tile * 16;
                int ar = row0 + lm; if (ar > S_ - 1) ar = S_ - 1;   // clamp pad rows

                f32x4 acc[4];
                #pragma unroll
                for (int nt = 0; nt < 4; ++nt) acc[nt] = (f32x4){0.f, 0.f, 0.f, 0.f};
                #pragma unroll
                for (int kt = 0; kt < 4; ++kt) {
                    int c = (kt * 4 + q) ^ (ar & 15);
                    short8_t av = *(const short8_t*)((const char*)hb + ar * 256 + c * 16);
                    #pragma unroll
                    for (int nt = 0; nt < 4; ++nt)
                        acc[nt] = __builtin_amdgcn_mfma_f32_16x16x32_bf16(av, bfrag[kt * 4 + nt], acc[nt], 0, 0, 0);
                }
                // epilogue: +tproj, relu, dot O (O_bias softmax-invariant)
                float part[4];
                #pragma unroll
                for (int r = 0; r < 4; ++r) {
                    float sum = 0.f;
                    #pragma unroll
                    for (int nt = 0; nt < 4; ++nt) {
                        int h = nt * 16 + lm;
                        float v = acc[nt][r] + th[nt];
                        v = fmaxf(v, 0.f);
                        sum = fmaf(v, ov_s[h], sum);
                    }
                    part[r] = sum;
                }
                #pragma unroll
                for (int off = 1; off < 16; off <<= 1) {
                    #pragma unroll
                    for (int r = 0; r < 4; ++r)
                        part[r] += __shfl_xor(part[r], off);
                }
                if (lm == 0) {
                    #pragma unroll
                    for (int r = 0; r < 4; ++r)
                        alph[row0 + q * 4 + r] = part[r];
                }
            }
        }
        bar();   // A: alpha ready

        // ---- softmax over s = 0..199 (8 waves) ----
        float a = (t < S_) ? alph[t] - mk * MASK_SCALE : -INFINITY;
        float m = a;
        #pragma unroll
        for (int off = 1; off < 64; off <<= 1) m = fmaxf(m, __shfl_xor(m, off));
        if (lane == 0) red8[wv] = m;
        bar();   // B: per-wave maxima ready
        m = red8[0];
        #pragma unroll
        for (int k = 1; k < 8; ++k) m = fmaxf(m, red8[k]);
        float e = (t < S_) ? __expf(a - m) : 0.f;
        if (t < S_) attw[t] = e;
        float ssum = e;
        #pragma unroll
        for (int off = 1; off < 64; off <<= 1) ssum += __shfl_xor(ssum, off);
        if (lane == 0) red8b[wv] = ssum;
        bar();   // C: attw + per-wave sums ready
        float tot = red8b[0];
        #pragma unroll
        for (int k = 1; k < 8; ++k) tot += red8b[k];
        const float inv = 1.f / tot;

        // ---- pooling (current buffer) ----
        const int d8 = t & 31;           // 8B index: d = d8*4 .. d8*4+3
        const int sg = t >> 5;           // 0..15 s-groups
        float acc0 = 0.f, acc1 = 0.f, acc2 = 0.f, acc3 = 0.f;
        for (int s = sg; s < S_; s += 16) {
            float w = attw[s];           // half-wave-uniform broadcast
            int pc = (d8 >> 1) ^ (s & 15);
            ushort4_t v = *(const ushort4_t*)((const char*)hb + s * 256 + pc * 16 + (d8 & 1) * 8);
            acc0 = fmaf(w, bf2f(v[0]), acc0);
            acc1 = fmaf(w, bf2f(v[1]), acc1);
            acc2 = fmaf(w, bf2f(v[2]), acc2);
            acc3 = fmaf(w, bf2f(v[3]), acc3);
        }
        acc0 += __shfl_xor(acc0, 32);
        acc1 += __shfl_xor(acc1, 32);
        acc2 += __shfl_xor(acc2, 32);
        acc3 += __shfl_xor(acc3, 32);
        if (wv && lane < 32) {
            float4 p; p.x = acc0; p.y = acc1; p.z = acc2; p.w = acc3;
            *(float4*)(&pool_s[(wv - 1) * D_ + d8 * 4]) = p;
        }

        // ---- convert + write next buffer, next tproj partials ----
        if (more) {
            unsigned short* hn = hisb[cur ^ 1];
            #pragma unroll
            for (int j = 0; j < 13; ++j) {
                int i = t + j * 512;
                if (i < 6400) {
                    int s = i >> 5, d8c = i & 31;
                    int pc = (d8c >> 1) ^ (s & 15);
                    uint2 v;
                    v.x = cvt_pk_bf16(x[j].x, x[j].y);
                    v.y = cvt_pk_bf16(x[j].z, x[j].w);
                    *(uint2*)((char*)hn + s * 256 + pc * 16 + (d8c & 1) * 8) = v;
                }
            }
            float acc = wb;
            #pragma unroll
            for (int k = 0; k < 4; ++k) {
                acc = fmaf(tg[k].x, wsl[k].x, acc);
                acc = fmaf(tg[k].y, wsl[k].y, acc);
                acc = fmaf(tg[k].z, wsl[k].z, acc);
                acc = fmaf(tg[k].w, wsl[k].w, acc);
            }
            tpp[wv * 64 + lane] = acc;
        }
        bar();   // D: pool partials + next buffer + next tpp ready

        if (wv == 0 && lane < 32) {
            #pragma unroll
            for (int k = 0; k < 7; ++k) {
                const float4 p = *(const float4*)(&pool_s[k * D_ + d8 * 4]);
                acc0 += p.x; acc1 += p.y; acc2 += p.z; acc3 += p.w;
            }
            float4 o;
            o.x = acc0 * inv; o.y = acc1 * inv; o.z = acc2 * inv; o.w = acc3 * inv;
            *(float4*)(out + (size_t)b * D_ + d8 * 4) = o;
        }

        mk = mkn;
        cur ^= 1;
    }
}

// ---------------------------------------------------------------------------
extern "C" void kernel_launch(void* const* d_in, const int* in_sizes, int n_in,
                              void* d_out, int out_size, void* d_ws, size_t ws_size,
                              hipStream_t stream) {
    const float* his    = (const float*)d_in[0];
    const float* target = (const float*)d_in[1];
    const float* mask   = (const float*)d_in[2];
    const float* W      = (const float*)d_in[3];
    const float* W_bias = (const float*)d_in[4];
    const float* Ovec   = (const float*)d_in[5];
    // O_bias (d_in[6]) is softmax-invariant -> unused
    float* out = (float*)d_out;

    char* ws = (char*)d_ws;
    unsigned short* wfrag = (unsigned short*)ws;           // 16 KB
    float* w23t           = (float*)(ws + 16384);          // 32 KB, (W3-W2)^T [h][d]

    prep<<<32, 256, 0, stream>>>(W, wfrag, w23t);
    fused_kernel<<<GRID_, 512, 0, stream>>>(his, mask, target, W_bias, wfrag, w23t, Ovec, out);
}